// Round 8
// baseline (479.458 us; speedup 1.0000x reference)
//
#include <hip/hip_runtime.h>

// 4D conv net, MI355X. S=30, B=2, ch 1->10->10->1, kernel 3^4, pad 1, ReLU.
// out = net(x,w) + net(x,w_swap), w_swap has (k1,k2)<->(k3,k4).
// R7: all layers as 32x32x16 bf16 MFMA, M = 32 padded t-positions, K = 16
// channels, N = k4*10+co. Cross-k4 combine in epilogue via per-wave LDS.
// R8: XCD-chunk swizzle, full-line stores, barrier-free epilogue.
// R12: uniform straight-line tap body (junk rows). R13: layer-0 K-packed
// (9 taps -> 1 tap, 12 MFMAs) as conv0_k.
// R14 (reverted): sched_barrier(0) ping-pong — fences blocked VALU/MFMA
// interleave, occupancy fell, regression.
// R15: the limit is outstanding-bytes (Little's law): 85 MB / 72 us =
// 1.2 TB/s effective vs 3.45 TB/s the same pattern sustained in R8 with
// more requests in flight; ~2.1 waves/SIMD x 9 KB in flight is 10x short
// of covering ~600 cy latency. Robust lever = more waves, blocked by
// acc=64 AGPR. => 8 waves x 2 rows (acc f32x16[2]=32 regs, ~120/wave,
// 4 waves/SIMD): resident waves/CU ~2x. Same MFMA total, A-loads +33%
// (L2-absorbed). Tap loop = known-good R13 rotate (no fences).

static constexpr int S  = 30;
static constexpr long S4 = 810000;
static constexpr size_t PLANE = 32768;                  // 32*32*16*2 B
static constexpr size_t YBYTES = (size_t)1800 * PLANE;  // [b(2)][g1][g2]

typedef __bf16 bf16x8 __attribute__((ext_vector_type(8)));
typedef float  f32x16 __attribute__((ext_vector_type(16)));
typedef unsigned int  u32;
typedef unsigned short u16;

static __device__ __forceinline__ u16 f2bf(float f) {
    u32 u = __builtin_bit_cast(u32, f);
    return (u16)((u + 0x7fffu + ((u >> 16) & 1u)) >> 16);
}

// ---------------------------------------------------------------------------
// B-fragment tables.
// Main: [set(6)][k12(9)][k3(3)][lane(64)] uint4 (sets 0/1 unused).
// L0-packed (appended): [branch(2)][k3(3)][lane(64)] uint4,
//   B[k=k12][n=k4*10+co] = w1[co, perm(k1,k2,k3,k4)], k12 = hl*8+j (<9).
__global__ __launch_bounds__(256) void fragprep_k(u32* __restrict__ ft,
    const float* __restrict__ w1, const float* __restrict__ w2,
    const float* __restrict__ w3)
{
    const int gid = blockIdx.x * 256 + threadIdx.x;
    if (gid >= 6 * 27 * 64 + 2 * 3 * 64) return;
    const int lane = gid & 63;
    const int n = lane & 31, hl = lane >> 5;
    u16 us[8];
#pragma unroll
    for (int j = 0; j < 8; ++j) us[j] = 0;

    if (gid < 6 * 27 * 64) {
        int r = gid >> 6;
        const int k3 = r % 3; r /= 3;
        const int k12 = r % 9; const int set = r / 9;
        const int layer = set >> 1, swap = set & 1;
        const int k1 = k12 / 3, k2 = k12 % 3;
        if (n < 30) {
            const int k4 = (n < 10) ? 0 : ((n < 20) ? 1 : 2);
            const int co = n - 10 * k4;
            const int i1 = swap ? k3 : k1, i2 = swap ? k4 : k2;
            const int i3 = swap ? k1 : k3, i4 = swap ? k2 : k4;
            const int widx = ((i1 * 3 + i2) * 3 + i3) * 3 + i4;
#pragma unroll
            for (int j = 0; j < 8; ++j) {
                const int k = hl * 8 + j;
                float wv = 0.f;
                if (layer == 0) { if (k == 0) wv = w1[co * 81 + widx]; }
                else if (layer == 1) { if (k < 10) wv = w2[(co * 10 + k) * 81 + widx]; }
                else { if (k < 10 && co == 0) wv = w3[k * 81 + widx]; }
                us[j] = f2bf(wv);
            }
        }
    } else {
        const int idx = gid - 6 * 27 * 64;       // 0..383
        int r = idx >> 6;                        // 0..5
        const int k3 = r % 3, swap = r / 3;
        if (n < 30) {
            const int k4 = (n < 10) ? 0 : ((n < 20) ? 1 : 2);
            const int co = n - 10 * k4;
#pragma unroll
            for (int j = 0; j < 8; ++j) {
                const int k12 = hl * 8 + j;
                if (k12 < 9) {
                    const int k1 = k12 / 3, k2 = k12 % 3;
                    const int i1 = swap ? k3 : k1, i2 = swap ? k4 : k2;
                    const int i3 = swap ? k1 : k3, i4 = swap ? k2 : k4;
                    const int widx = ((i1 * 3 + i2) * 3 + i3) * 3 + i4;
                    us[j] = f2bf(w1[co * 81 + widx]);
                }
            }
        }
    }
    u32* o = ft + (size_t)gid * 4;
    o[0] = (u32)us[0] | ((u32)us[1] << 16);
    o[1] = (u32)us[2] | ((u32)us[3] << 16);
    o[2] = (u32)us[4] | ((u32)us[5] << 16);
    o[3] = (u32)us[6] | ((u32)us[7] << 16);
}

// ---------------------------------------------------------------------------
// Zero halo positions (h' or t' in {0,31}) of all 1800 planes of y1 and y2.
__global__ __launch_bounds__(128) void zerok(u16* __restrict__ y1, u16* __restrict__ y2)
{
    const int pb = blockIdx.x, tid = threadIdx.x;
    if (tid >= 124) return;
    int hp, tp;
    if (tid < 32)      { hp = 0;        tp = tid; }
    else if (tid < 64) { hp = 31;       tp = tid - 32; }
    else if (tid < 94) { hp = tid - 63; tp = 0; }
    else               { hp = tid - 93; tp = 31; }
    const size_t off = (size_t)pb * PLANE + hp * 1024 + tp * 32;
    const uint4 z = make_uint4(0, 0, 0, 0);
    *(uint4*)((char*)y1 + off)      = z;
    *(uint4*)((char*)y1 + off + 16) = z;
    *(uint4*)((char*)y2 + off)      = z;
    *(uint4*)((char*)y2 + off + 16) = z;
}

// ---------------------------------------------------------------------------
// Layer 0, K-packed: one "tap", 12 MFMAs per wave (unchanged from R13).
__global__ __launch_bounds__(256, 4) void conv0_k(
    const float* __restrict__ x, const uint4* __restrict__ bt,
    const float* __restrict__ bias, void* __restrict__ outp)
{
    __shared__ float E[4][1056];
    const int wgid = blockIdx.x + S * blockIdx.y + 900 * blockIdx.z;
    const int id2  = (wgid & 7) * 450 + (wgid >> 3);
    const int half = id2 & 1;
    int sp = id2 >> 1;
    const int w1i = sp % S; sp /= S;
    const int h1  = sp % S;
    const int b   = sp / S;

    const int tid = threadIdx.x;
    const int lane = tid & 63, wv = tid >> 6;
    const int m = lane & 31, hl = lane >> 5;
    const int rbase = half * 15 + wv * 4;

    uint4 Bs[3];
#pragma unroll
    for (int ss = 0; ss < 3; ++ss) Bs[ss] = bt[ss * 64 + lane];

    int gof[9]; int gokm = 0;
#pragma unroll
    for (int k12 = 0; k12 < 9; ++k12) {
        const int g1 = h1 + k12 / 3 - 1, g2 = w1i + k12 % 3 - 1;
        gof[k12] = 0;
        if (g1 >= 0 && g1 < S && g2 >= 0 && g2 < S) {
            gof[k12] = (g1 * S + g2) * 900; gokm |= 1 << k12;
        }
    }
    const float* xb = x + (size_t)b * S4;

    uint4 F[6];
#pragma unroll
    for (int f = 0; f < 6; ++f) {
        const int hp = rbase + f;
        const bool rk = (hp >= 1 && hp <= 30 && m >= 1 && m <= 30);
        const int ro = (hp - 1) * 30 + (m - 1);
        u16 av[8];
#pragma unroll
        for (int j = 0; j < 8; ++j) av[j] = 0;
        if (hl == 0) {
#pragma unroll
            for (int j = 0; j < 8; ++j) {
                float v = 0.f;
                if (rk && ((gokm >> j) & 1)) v = xb[gof[j] + ro];
                av[j] = f2bf(v);
            }
        } else {
            float v = 0.f;
            if (rk && ((gokm >> 8) & 1)) v = xb[gof[8] + ro];
            av[0] = f2bf(v);
        }
        F[f] = make_uint4((u32)av[0] | ((u32)av[1] << 16),
                          (u32)av[2] | ((u32)av[3] << 16),
                          (u32)av[4] | ((u32)av[5] << 16),
                          (u32)av[6] | ((u32)av[7] << 16));
    }

    f32x16 acc[4];
#pragma unroll
    for (int r = 0; r < 4; ++r)
#pragma unroll
        for (int e = 0; e < 16; ++e) acc[r][e] = 0.f;
#pragma unroll
    for (int ss = 0; ss < 3; ++ss)
#pragma unroll
        for (int r = 0; r < 4; ++r)
            acc[r] = __builtin_amdgcn_mfma_f32_32x32x16_bf16(
                __builtin_bit_cast(bf16x8, F[r + ss]),
                __builtin_bit_cast(bf16x8, Bs[ss]), acc[r], 0, 0, 0);

    float* Ew = E[wv];
    for (int r = 0; r < 4; ++r) {
        if (wv == 3 && r == 3) continue;
#pragma unroll
        for (int gq = 0; gq < 4; ++gq)
#pragma unroll
            for (int r4 = 0; r4 < 4; ++r4)
                Ew[m * 33 + 4 * hl + 8 * gq + r4] = acc[r][gq * 4 + r4];

        const int h2 = rbase + r;
        char* pl = (char*)outp + ((size_t)b * 900 + h1 * S + w1i) * PLANE
                   + (size_t)(h2 + 1) * 1024;
        const int t = lane >> 1, h8 = lane & 1;
        if (t < 30) {
            u32 wo[4];
#pragma unroll
            for (int p = 0; p < 4; ++p) {
                const int c0 = 8 * h8 + 2 * p, c1 = c0 + 1;
                float v0 = 0.f, v1 = 0.f;
                if (c0 < 10)
                    v0 = fmaxf(Ew[c0 * 33 + t] + Ew[(10 + c0) * 33 + t + 1]
                             + Ew[(20 + c0) * 33 + t + 2] + bias[c0], 0.f);
                if (c1 < 10)
                    v1 = fmaxf(Ew[c1 * 33 + t] + Ew[(10 + c1) * 33 + t + 1]
                             + Ew[(20 + c1) * 33 + t + 2] + bias[c1], 0.f);
                wo[p] = (u32)f2bf(v0) | ((u32)f2bf(v1) << 16);
            }
            *(uint4*)(pl + (t + 1) * 32 + h8 * 16) =
                make_uint4(wo[0], wo[1], wo[2], wo[3]);
        }
    }
}

// ---------------------------------------------------------------------------
// Layers 1/2: 8 waves x 2 rows. Wave wv owns h2 rows rbase..rbase+1,
// rbase = half*15 + wv*2 (wave 7 row 1 junk -> fully uniform tap body).
// Per tap: 4 A-loads + 3 B-loads + 6 MFMAs. Depth-1 rotate pipeline
// (known-good R13 form, no scheduling fences).
template<int LAYER, bool ACCUM>
__global__ __launch_bounds__(512, 4) void conv_k(
    const void* __restrict__ inp, const u32* __restrict__ ftab,
    const float* __restrict__ bias, void* __restrict__ outp)
{
    __shared__ float E[8][1056];
    const int wgid = blockIdx.x + S * blockIdx.y + 900 * blockIdx.z;
    const int id2  = (wgid & 7) * 450 + (wgid >> 3);
    const int half = id2 & 1;
    int sp = id2 >> 1;
    const int w1i = sp % S; sp /= S;
    const int h1  = sp % S;
    const int b   = sp / S;

    const int tid = threadIdx.x;
    const int lane = tid & 63, wv = tid >> 6;
    const int m = lane & 31, hl = lane >> 5;
    const int rbase = half * 15 + wv * 2;
    const uint4* ft4 = (const uint4*)ftab;

    int rofs[4];
#pragma unroll
    for (int f = 0; f < 4; ++f) {
        int rr = rbase + f; if (rr > 31) rr = 31;
        rofs[f] = rr * 1024;
    }

    int kl[9], nk = 0;
#pragma unroll
    for (int k12 = 0; k12 < 9; ++k12) {
        const int g1 = h1 + k12 / 3 - 1, g2 = w1i + k12 % 3 - 1;
        if (g1 >= 0 && g1 < S && g2 >= 0 && g2 < S)
            kl[nk++] = (g1 * S + g2) | (k12 << 10);
    }

    f32x16 acc[2];
#pragma unroll
    for (int r = 0; r < 2; ++r)
#pragma unroll
        for (int e = 0; e < 16; ++e) acc[r][e] = 0.f;

    auto loadA = [&](uint4* Fd, int g) {
        const char* P = (const char*)inp + ((size_t)b * 900 + g) * PLANE
                        + m * 32 + hl * 16;
#pragma unroll
        for (int f = 0; f < 4; ++f)
            Fd[f] = *(const uint4*)(P + rofs[f]);
    };

    uint4 B0[3];
    {
        const int k0 = kl[0] >> 10;
#pragma unroll
        for (int f = 0; f < 3; ++f) B0[f] = ft4[(k0 * 3 + f) * 64 + lane];
    }
    uint4 F[4];
    loadA(F, kl[0] & 1023);

    for (int ki = 0; ki + 1 < nk; ++ki) {
        const int gn = kl[ki + 1] & 1023, kn = kl[ki + 1] >> 10;
        uint4 FN[4];
        loadA(FN, gn);
        uint4 BN[3];
#pragma unroll
        for (int f = 0; f < 3; ++f) BN[f] = ft4[(kn * 3 + f) * 64 + lane];

        // s-outer / r-inner: 2 independent MFMAs between dependent pairs
#pragma unroll
        for (int ss = 0; ss < 3; ++ss)
#pragma unroll
            for (int r = 0; r < 2; ++r)
                acc[r] = __builtin_amdgcn_mfma_f32_32x32x16_bf16(
                    __builtin_bit_cast(bf16x8, F[r + ss]),
                    __builtin_bit_cast(bf16x8, B0[ss]), acc[r], 0, 0, 0);

#pragma unroll
        for (int f = 0; f < 4; ++f) F[f] = FN[f];
#pragma unroll
        for (int f = 0; f < 3; ++f) B0[f] = BN[f];
    }
#pragma unroll
    for (int ss = 0; ss < 3; ++ss)
#pragma unroll
        for (int r = 0; r < 2; ++r)
            acc[r] = __builtin_amdgcn_mfma_f32_32x32x16_bf16(
                __builtin_bit_cast(bf16x8, F[r + ss]),
                __builtin_bit_cast(bf16x8, B0[ss]), acc[r], 0, 0, 0);

    // ---- epilogue: per-wave LDS transpose, combine k4 shifts ----
    float* Ew = E[wv];
    for (int r = 0; r < 2; ++r) {
        if (wv == 7 && r == 1) continue;             // junk row, wave-uniform
#pragma unroll
        for (int gq = 0; gq < 4; ++gq)
#pragma unroll
            for (int r4 = 0; r4 < 4; ++r4)
                Ew[m * 33 + 4 * hl + 8 * gq + r4] = acc[r][gq * 4 + r4];

        const int h2 = rbase + r;
        if (LAYER <= 1) {
            char* pl = (char*)outp + ((size_t)b * 900 + h1 * S + w1i) * PLANE
                       + (size_t)(h2 + 1) * 1024;
            const int t = lane >> 1, h8 = lane & 1;
            if (t < 30) {
                u32 wo[4];
#pragma unroll
                for (int p = 0; p < 4; ++p) {
                    const int c0 = 8 * h8 + 2 * p, c1 = c0 + 1;
                    float v0 = 0.f, v1 = 0.f;
                    if (c0 < 10)
                        v0 = fmaxf(Ew[c0 * 33 + t] + Ew[(10 + c0) * 33 + t + 1]
                                 + Ew[(20 + c0) * 33 + t + 2] + bias[c0], 0.f);
                    if (c1 < 10)
                        v1 = fmaxf(Ew[c1 * 33 + t] + Ew[(10 + c1) * 33 + t + 1]
                                 + Ew[(20 + c1) * 33 + t + 2] + bias[c1], 0.f);
                    wo[p] = (u32)f2bf(v0) | ((u32)f2bf(v1) << 16);
                }
                *(uint4*)(pl + (t + 1) * 32 + h8 * 16) =
                    make_uint4(wo[0], wo[1], wo[2], wo[3]);
            }
        } else {
            if (lane < 30) {
                const int t = lane;
                float v = Ew[t] + Ew[330 + t + 1] + Ew[660 + t + 2] + bias[0];
                v = fmaxf(v, 0.f);
                float* o = (float*)outp + (size_t)b * S4
                           + (size_t)(h1 * S + w1i) * 900 + h2 * 30 + t;
                if (ACCUM) *o += v; else *o = v;
            }
        }
    }
}

// ---------------------------------------------------------------------------
extern "C" void kernel_launch(void* const* d_in, const int* in_sizes, int n_in,
                              void* d_out, int out_size, void* d_ws, size_t ws_size,
                              hipStream_t stream)
{
    const float* x   = (const float*)d_in[0];
    const float* w1p = (const float*)d_in[1];
    const float* b1p = (const float*)d_in[2];
    const float* w2p = (const float*)d_in[3];
    const float* b2p = (const float*)d_in[4];
    const float* w3p = (const float*)d_in[5];
    const float* b3p = (const float*)d_in[6];
    float* out = (float*)d_out;

    // ws: fragtab (6*27*64 + 2*3*64) uint4 = 172032 B | y1 59 MB | y2 59 MB
    u32* ft = (u32*)d_ws;
    const uint4* ftL0 = (const uint4*)d_ws + 6 * 27 * 64;
    u16* y1 = (u16*)((char*)d_ws + 172032);
    u16* y2 = (u16*)((char*)y1 + YBYTES);

    fragprep_k<<<42, 256, 0, stream>>>(ft, w1p, w2p, w3p);
    zerok<<<1800, 128, 0, stream>>>(y1, y2);

    dim3 grid(S, S, 4);
    for (int br = 0; br < 2; ++br) {
        const u32* f2 = ft + (size_t)(2 + br) * 27 * 64 * 4;
        const u32* f3 = ft + (size_t)(4 + br) * 27 * 64 * 4;
        conv0_k<<<grid, 256, 0, stream>>>(x, ftL0 + br * 192, b1p, (void*)y1);
        conv_k<1, false><<<grid, 512, 0, stream>>>(y1, f2, b2p, (void*)y2);
        if (br == 0)
            conv_k<2, false><<<grid, 512, 0, stream>>>(y2, f3, b3p, (void*)out);
        else
            conv_k<2, true><<<grid, 512, 0, stream>>>(y2, f3, b3p, (void*)out);
    }
}

// Round 9
// 446.043 us; speedup vs baseline: 1.0749x; 1.0749x over previous
//
#include <hip/hip_runtime.h>

// 4D conv net, MI355X. S=30, B=2, ch 1->10->10->1, kernel 3^4, pad 1, ReLU.
// out = net(x,w) + net(x,w_swap), w_swap has (k1,k2)<->(k3,k4).
// R7: all layers as 32x32x16 bf16 MFMA, M = 32 padded t-positions, K = 16
// channels, N = k4*10+co. Cross-k4 combine in epilogue via per-wave LDS.
// R8: XCD-chunk swizzle, full-line stores, barrier-free epilogue.
// R12: uniform straight-line tap body (junk rows). R13: layer-0 K-packed
// (9 taps -> 1 tap, 12 MFMAs) as conv0_k. Best conv_k: 72 us/dispatch.
// R14 (fences) / R15 (8-wave): both regressed; see journal.
// R16: root cause of the pinned ~600cy/tap stall: rotate copies F=FN make
// the allocator COALESCE FN onto F's physical regs -> FN loads WRITE the
// regs the current MFMAs READ (WAR) -> loads can't issue until the MFMA
// block consumes F -> prefetch distance ~100cy regardless of source order.
// R14's VGPR=96 proved ping-pong (distinct live ranges, no copies) breaks
// the coalescing; its regression was the sched_barrier fences. R16 = R14
// ping-pong WITHOUT fences: scheduler free to hoist state-X loads above
// state-Y MFMAs. Verify: VGPR ~96-130, dur 72 -> ~55-62.

static constexpr int S  = 30;
static constexpr long S4 = 810000;
static constexpr size_t PLANE = 32768;                  // 32*32*16*2 B
static constexpr size_t YBYTES = (size_t)1800 * PLANE;  // [b(2)][g1][g2]

typedef __bf16 bf16x8 __attribute__((ext_vector_type(8)));
typedef float  f32x16 __attribute__((ext_vector_type(16)));
typedef unsigned int  u32;
typedef unsigned short u16;

static __device__ __forceinline__ u16 f2bf(float f) {
    u32 u = __builtin_bit_cast(u32, f);
    return (u16)((u + 0x7fffu + ((u >> 16) & 1u)) >> 16);
}

// ---------------------------------------------------------------------------
// B-fragment tables.
// Main: [set(6)][k12(9)][k3(3)][lane(64)] uint4 (sets 0/1 unused).
// L0-packed (appended): [branch(2)][k3(3)][lane(64)] uint4,
//   B[k=k12][n=k4*10+co] = w1[co, perm(k1,k2,k3,k4)], k12 = hl*8+j (<9).
__global__ __launch_bounds__(256) void fragprep_k(u32* __restrict__ ft,
    const float* __restrict__ w1, const float* __restrict__ w2,
    const float* __restrict__ w3)
{
    const int gid = blockIdx.x * 256 + threadIdx.x;
    if (gid >= 6 * 27 * 64 + 2 * 3 * 64) return;
    const int lane = gid & 63;
    const int n = lane & 31, hl = lane >> 5;
    u16 us[8];
#pragma unroll
    for (int j = 0; j < 8; ++j) us[j] = 0;

    if (gid < 6 * 27 * 64) {
        int r = gid >> 6;
        const int k3 = r % 3; r /= 3;
        const int k12 = r % 9; const int set = r / 9;
        const int layer = set >> 1, swap = set & 1;
        const int k1 = k12 / 3, k2 = k12 % 3;
        if (n < 30) {
            const int k4 = (n < 10) ? 0 : ((n < 20) ? 1 : 2);
            const int co = n - 10 * k4;
            const int i1 = swap ? k3 : k1, i2 = swap ? k4 : k2;
            const int i3 = swap ? k1 : k3, i4 = swap ? k2 : k4;
            const int widx = ((i1 * 3 + i2) * 3 + i3) * 3 + i4;
#pragma unroll
            for (int j = 0; j < 8; ++j) {
                const int k = hl * 8 + j;
                float wv = 0.f;
                if (layer == 0) { if (k == 0) wv = w1[co * 81 + widx]; }
                else if (layer == 1) { if (k < 10) wv = w2[(co * 10 + k) * 81 + widx]; }
                else { if (k < 10 && co == 0) wv = w3[k * 81 + widx]; }
                us[j] = f2bf(wv);
            }
        }
    } else {
        const int idx = gid - 6 * 27 * 64;       // 0..383
        int r = idx >> 6;                        // 0..5
        const int k3 = r % 3, swap = r / 3;
        if (n < 30) {
            const int k4 = (n < 10) ? 0 : ((n < 20) ? 1 : 2);
            const int co = n - 10 * k4;
#pragma unroll
            for (int j = 0; j < 8; ++j) {
                const int k12 = hl * 8 + j;
                if (k12 < 9) {
                    const int k1 = k12 / 3, k2 = k12 % 3;
                    const int i1 = swap ? k3 : k1, i2 = swap ? k4 : k2;
                    const int i3 = swap ? k1 : k3, i4 = swap ? k2 : k4;
                    const int widx = ((i1 * 3 + i2) * 3 + i3) * 3 + i4;
                    us[j] = f2bf(w1[co * 81 + widx]);
                }
            }
        }
    }
    u32* o = ft + (size_t)gid * 4;
    o[0] = (u32)us[0] | ((u32)us[1] << 16);
    o[1] = (u32)us[2] | ((u32)us[3] << 16);
    o[2] = (u32)us[4] | ((u32)us[5] << 16);
    o[3] = (u32)us[6] | ((u32)us[7] << 16);
}

// ---------------------------------------------------------------------------
// Zero halo positions (h' or t' in {0,31}) of all 1800 planes of y1 and y2.
__global__ __launch_bounds__(128) void zerok(u16* __restrict__ y1, u16* __restrict__ y2)
{
    const int pb = blockIdx.x, tid = threadIdx.x;
    if (tid >= 124) return;
    int hp, tp;
    if (tid < 32)      { hp = 0;        tp = tid; }
    else if (tid < 64) { hp = 31;       tp = tid - 32; }
    else if (tid < 94) { hp = tid - 63; tp = 0; }
    else               { hp = tid - 93; tp = 31; }
    const size_t off = (size_t)pb * PLANE + hp * 1024 + tp * 32;
    const uint4 z = make_uint4(0, 0, 0, 0);
    *(uint4*)((char*)y1 + off)      = z;
    *(uint4*)((char*)y1 + off + 16) = z;
    *(uint4*)((char*)y2 + off)      = z;
    *(uint4*)((char*)y2 + off + 16) = z;
}

// ---------------------------------------------------------------------------
// Layer 0, K-packed: one "tap", 12 MFMAs per wave (unchanged from R13).
__global__ __launch_bounds__(256, 4) void conv0_k(
    const float* __restrict__ x, const uint4* __restrict__ bt,
    const float* __restrict__ bias, void* __restrict__ outp)
{
    __shared__ float E[4][1056];
    const int wgid = blockIdx.x + S * blockIdx.y + 900 * blockIdx.z;
    const int id2  = (wgid & 7) * 450 + (wgid >> 3);
    const int half = id2 & 1;
    int sp = id2 >> 1;
    const int w1i = sp % S; sp /= S;
    const int h1  = sp % S;
    const int b   = sp / S;

    const int tid = threadIdx.x;
    const int lane = tid & 63, wv = tid >> 6;
    const int m = lane & 31, hl = lane >> 5;
    const int rbase = half * 15 + wv * 4;

    uint4 Bs[3];
#pragma unroll
    for (int ss = 0; ss < 3; ++ss) Bs[ss] = bt[ss * 64 + lane];

    int gof[9]; int gokm = 0;
#pragma unroll
    for (int k12 = 0; k12 < 9; ++k12) {
        const int g1 = h1 + k12 / 3 - 1, g2 = w1i + k12 % 3 - 1;
        gof[k12] = 0;
        if (g1 >= 0 && g1 < S && g2 >= 0 && g2 < S) {
            gof[k12] = (g1 * S + g2) * 900; gokm |= 1 << k12;
        }
    }
    const float* xb = x + (size_t)b * S4;

    uint4 F[6];
#pragma unroll
    for (int f = 0; f < 6; ++f) {
        const int hp = rbase + f;
        const bool rk = (hp >= 1 && hp <= 30 && m >= 1 && m <= 30);
        const int ro = (hp - 1) * 30 + (m - 1);
        u16 av[8];
#pragma unroll
        for (int j = 0; j < 8; ++j) av[j] = 0;
        if (hl == 0) {
#pragma unroll
            for (int j = 0; j < 8; ++j) {
                float v = 0.f;
                if (rk && ((gokm >> j) & 1)) v = xb[gof[j] + ro];
                av[j] = f2bf(v);
            }
        } else {
            float v = 0.f;
            if (rk && ((gokm >> 8) & 1)) v = xb[gof[8] + ro];
            av[0] = f2bf(v);
        }
        F[f] = make_uint4((u32)av[0] | ((u32)av[1] << 16),
                          (u32)av[2] | ((u32)av[3] << 16),
                          (u32)av[4] | ((u32)av[5] << 16),
                          (u32)av[6] | ((u32)av[7] << 16));
    }

    f32x16 acc[4];
#pragma unroll
    for (int r = 0; r < 4; ++r)
#pragma unroll
        for (int e = 0; e < 16; ++e) acc[r][e] = 0.f;
#pragma unroll
    for (int ss = 0; ss < 3; ++ss)
#pragma unroll
        for (int r = 0; r < 4; ++r)
            acc[r] = __builtin_amdgcn_mfma_f32_32x32x16_bf16(
                __builtin_bit_cast(bf16x8, F[r + ss]),
                __builtin_bit_cast(bf16x8, Bs[ss]), acc[r], 0, 0, 0);

    float* Ew = E[wv];
    for (int r = 0; r < 4; ++r) {
        if (wv == 3 && r == 3) continue;
#pragma unroll
        for (int gq = 0; gq < 4; ++gq)
#pragma unroll
            for (int r4 = 0; r4 < 4; ++r4)
                Ew[m * 33 + 4 * hl + 8 * gq + r4] = acc[r][gq * 4 + r4];

        const int h2 = rbase + r;
        char* pl = (char*)outp + ((size_t)b * 900 + h1 * S + w1i) * PLANE
                   + (size_t)(h2 + 1) * 1024;
        const int t = lane >> 1, h8 = lane & 1;
        if (t < 30) {
            u32 wo[4];
#pragma unroll
            for (int p = 0; p < 4; ++p) {
                const int c0 = 8 * h8 + 2 * p, c1 = c0 + 1;
                float v0 = 0.f, v1 = 0.f;
                if (c0 < 10)
                    v0 = fmaxf(Ew[c0 * 33 + t] + Ew[(10 + c0) * 33 + t + 1]
                             + Ew[(20 + c0) * 33 + t + 2] + bias[c0], 0.f);
                if (c1 < 10)
                    v1 = fmaxf(Ew[c1 * 33 + t] + Ew[(10 + c1) * 33 + t + 1]
                             + Ew[(20 + c1) * 33 + t + 2] + bias[c1], 0.f);
                wo[p] = (u32)f2bf(v0) | ((u32)f2bf(v1) << 16);
            }
            *(uint4*)(pl + (t + 1) * 32 + h8 * 16) =
                make_uint4(wo[0], wo[1], wo[2], wo[3]);
        }
    }
}

// ---------------------------------------------------------------------------
// Layers 1/2: 4 waves x 4 rows, ping-pong register double-buffer WITHOUT
// scheduling fences. Fa/Ba and Fb/Bb are distinct live ranges (no rotate
// copies -> no register coalescing -> no WAR between prefetch loads and
// current MFMAs -> loads hoist a full tap early).
template<int LAYER, bool ACCUM>
__global__ __launch_bounds__(256, 2) void conv_k(
    const void* __restrict__ inp, const u32* __restrict__ ftab,
    const float* __restrict__ bias, void* __restrict__ outp)
{
    __shared__ float E[4][1056];
    const int wgid = blockIdx.x + S * blockIdx.y + 900 * blockIdx.z;
    const int id2  = (wgid & 7) * 450 + (wgid >> 3);
    const int half = id2 & 1;
    int sp = id2 >> 1;
    const int w1i = sp % S; sp /= S;
    const int h1  = sp % S;
    const int b   = sp / S;

    const int tid = threadIdx.x;
    const int lane = tid & 63, wv = tid >> 6;
    const int m = lane & 31, hl = lane >> 5;
    const int rbase = half * 15 + wv * 4;
    const uint4* ft4 = (const uint4*)ftab;

    int rofs[6];
#pragma unroll
    for (int f = 0; f < 6; ++f) {
        int rr = rbase + f; if (rr > 31) rr = 31;
        rofs[f] = rr * 1024;
    }

    int kl[9], nk = 0;
#pragma unroll
    for (int k12 = 0; k12 < 9; ++k12) {
        const int g1 = h1 + k12 / 3 - 1, g2 = w1i + k12 % 3 - 1;
        if (g1 >= 0 && g1 < S && g2 >= 0 && g2 < S)
            kl[nk++] = (g1 * S + g2) | (k12 << 10);
    }

    f32x16 acc[4];
#pragma unroll
    for (int r = 0; r < 4; ++r)
#pragma unroll
        for (int e = 0; e < 16; ++e) acc[r][e] = 0.f;

    auto loadA = [&](uint4* Fd, int g) {
        const char* P = (const char*)inp + ((size_t)b * 900 + g) * PLANE
                        + m * 32 + hl * 16;
#pragma unroll
        for (int f = 0; f < 6; ++f)
            Fd[f] = *(const uint4*)(P + rofs[f]);
    };
    auto loadB = [&](uint4* Bd, int k) {
#pragma unroll
        for (int f = 0; f < 3; ++f) Bd[f] = ft4[(k * 3 + f) * 64 + lane];
    };
    auto mfma12 = [&](const uint4* Fs, const uint4* Bs) {
#pragma unroll
        for (int ss = 0; ss < 3; ++ss)
#pragma unroll
            for (int r = 0; r < 4; ++r)
                acc[r] = __builtin_amdgcn_mfma_f32_32x32x16_bf16(
                    __builtin_bit_cast(bf16x8, Fs[r + ss]),
                    __builtin_bit_cast(bf16x8, Bs[ss]), acc[r], 0, 0, 0);
    };

    uint4 Fa[6], Ba[3], Fb[6], Bb[3];
    loadA(Fa, kl[0] & 1023); loadB(Ba, kl[0] >> 10);

    int ki = 0;
    for (; ki + 2 < nk; ki += 2) {
        loadA(Fb, kl[ki + 1] & 1023); loadB(Bb, kl[ki + 1] >> 10);
        mfma12(Fa, Ba);
        loadA(Fa, kl[ki + 2] & 1023); loadB(Ba, kl[ki + 2] >> 10);
        mfma12(Fb, Bb);
    }
    if (ki + 1 < nk) {                        // 2 taps left
        loadA(Fb, kl[ki + 1] & 1023); loadB(Bb, kl[ki + 1] >> 10);
        mfma12(Fa, Ba);
        mfma12(Fb, Bb);
    } else {                                  // 1 tap left
        mfma12(Fa, Ba);
    }

    float* Ew = E[wv];
    for (int r = 0; r < 4; ++r) {
        if (wv == 3 && r == 3) continue;
#pragma unroll
        for (int gq = 0; gq < 4; ++gq)
#pragma unroll
            for (int r4 = 0; r4 < 4; ++r4)
                Ew[m * 33 + 4 * hl + 8 * gq + r4] = acc[r][gq * 4 + r4];

        const int h2 = rbase + r;
        if (LAYER <= 1) {
            char* pl = (char*)outp + ((size_t)b * 900 + h1 * S + w1i) * PLANE
                       + (size_t)(h2 + 1) * 1024;
            const int t = lane >> 1, h8 = lane & 1;
            if (t < 30) {
                u32 wo[4];
#pragma unroll
                for (int p = 0; p < 4; ++p) {
                    const int c0 = 8 * h8 + 2 * p, c1 = c0 + 1;
                    float v0 = 0.f, v1 = 0.f;
                    if (c0 < 10)
                        v0 = fmaxf(Ew[c0 * 33 + t] + Ew[(10 + c0) * 33 + t + 1]
                                 + Ew[(20 + c0) * 33 + t + 2] + bias[c0], 0.f);
                    if (c1 < 10)
                        v1 = fmaxf(Ew[c1 * 33 + t] + Ew[(10 + c1) * 33 + t + 1]
                                 + Ew[(20 + c1) * 33 + t + 2] + bias[c1], 0.f);
                    wo[p] = (u32)f2bf(v0) | ((u32)f2bf(v1) << 16);
                }
                *(uint4*)(pl + (t + 1) * 32 + h8 * 16) =
                    make_uint4(wo[0], wo[1], wo[2], wo[3]);
            }
        } else {
            if (lane < 30) {
                const int t = lane;
                float v = Ew[t] + Ew[330 + t + 1] + Ew[660 + t + 2] + bias[0];
                v = fmaxf(v, 0.f);
                float* o = (float*)outp + (size_t)b * S4
                           + (size_t)(h1 * S + w1i) * 900 + h2 * 30 + t;
                if (ACCUM) *o += v; else *o = v;
            }
        }
    }
}

// ---------------------------------------------------------------------------
extern "C" void kernel_launch(void* const* d_in, const int* in_sizes, int n_in,
                              void* d_out, int out_size, void* d_ws, size_t ws_size,
                              hipStream_t stream)
{
    const float* x   = (const float*)d_in[0];
    const float* w1p = (const float*)d_in[1];
    const float* b1p = (const float*)d_in[2];
    const float* w2p = (const float*)d_in[3];
    const float* b2p = (const float*)d_in[4];
    const float* w3p = (const float*)d_in[5];
    const float* b3p = (const float*)d_in[6];
    float* out = (float*)d_out;

    // ws: fragtab (6*27*64 + 2*3*64) uint4 = 172032 B | y1 59 MB | y2 59 MB
    u32* ft = (u32*)d_ws;
    const uint4* ftL0 = (const uint4*)d_ws + 6 * 27 * 64;
    u16* y1 = (u16*)((char*)d_ws + 172032);
    u16* y2 = (u16*)((char*)y1 + YBYTES);

    fragprep_k<<<42, 256, 0, stream>>>(ft, w1p, w2p, w3p);
    zerok<<<1800, 128, 0, stream>>>(y1, y2);

    dim3 grid(S, S, 4), blk(256);
    for (int br = 0; br < 2; ++br) {
        const u32* f2 = ft + (size_t)(2 + br) * 27 * 64 * 4;
        const u32* f3 = ft + (size_t)(4 + br) * 27 * 64 * 4;
        conv0_k<<<grid, blk, 0, stream>>>(x, ftL0 + br * 192, b1p, (void*)y1);
        conv_k<1, false><<<grid, blk, 0, stream>>>(y1, f2, b2p, (void*)y2);
        if (br == 0)
            conv_k<2, false><<<grid, blk, 0, stream>>>(y2, f3, b3p, (void*)out);
        else
            conv_k<2, true><<<grid, blk, 0, stream>>>(y2, f3, b3p, (void*)out);
    }
}

// Round 10
// 387.148 us; speedup vs baseline: 1.2384x; 1.1521x over previous
//
#include <hip/hip_runtime.h>

// 4D conv net, MI355X. S=30, B=2, ch 1->10->10->1, kernel 3^4, pad 1, ReLU.
// out = net(x,w) + net(x,w_swap), w_swap has (k1,k2)<->(k3,k4).
// R7: all layers as 32x32x16 bf16 MFMA, M = 32 padded t-positions, K = 16
// channels, N = k4*10+co. Cross-k4 combine in epilogue via per-wave LDS.
// R8: XCD-chunk swizzle, full-line stores, barrier-free epilogue.
// R12: uniform straight-line tap body (junk rows). R13: layer-0 K-packed
// (9 taps -> 1 tap, 12 MFMAs) as conv0_k. Best conv_k: 72 us/dispatch.
// R9/R14/R15/R16: four per-wave pipelining attempts all <= R13's simple
// rotate loop -> prefetch depth is NOT the lever; tap loop frozen at R13.
// R17: cut the TA/L2 load. Per dispatch ~1.2 GB L2 reads / 18.6M TA lines;
// ONE THIRD is the 27.6 KB block-invariant B-table re-fetched from global
// 108x per block (398 MB/dispatch). Stage it to LDS once per block (single
// prologue barrier); tap-loop B reads = ds_read_b128 on the idle DS pipe.
// Isolated change vs R13 (R11 bundled this with occupancy-killing changes).
// LDS 44.5 KB -> still 2 blocks/CU at (256,2).

static constexpr int S  = 30;
static constexpr long S4 = 810000;
static constexpr size_t PLANE = 32768;                  // 32*32*16*2 B
static constexpr size_t YBYTES = (size_t)1800 * PLANE;  // [b(2)][g1][g2]

typedef __bf16 bf16x8 __attribute__((ext_vector_type(8)));
typedef float  f32x16 __attribute__((ext_vector_type(16)));
typedef unsigned int  u32;
typedef unsigned short u16;

static __device__ __forceinline__ u16 f2bf(float f) {
    u32 u = __builtin_bit_cast(u32, f);
    return (u16)((u + 0x7fffu + ((u >> 16) & 1u)) >> 16);
}

// ---------------------------------------------------------------------------
// B-fragment tables.
// Main: [set(6)][k12(9)][k3(3)][lane(64)] uint4 (sets 0/1 unused).
// L0-packed (appended): [branch(2)][k3(3)][lane(64)] uint4,
//   B[k=k12][n=k4*10+co] = w1[co, perm(k1,k2,k3,k4)], k12 = hl*8+j (<9).
__global__ __launch_bounds__(256) void fragprep_k(u32* __restrict__ ft,
    const float* __restrict__ w1, const float* __restrict__ w2,
    const float* __restrict__ w3)
{
    const int gid = blockIdx.x * 256 + threadIdx.x;
    if (gid >= 6 * 27 * 64 + 2 * 3 * 64) return;
    const int lane = gid & 63;
    const int n = lane & 31, hl = lane >> 5;
    u16 us[8];
#pragma unroll
    for (int j = 0; j < 8; ++j) us[j] = 0;

    if (gid < 6 * 27 * 64) {
        int r = gid >> 6;
        const int k3 = r % 3; r /= 3;
        const int k12 = r % 9; const int set = r / 9;
        const int layer = set >> 1, swap = set & 1;
        const int k1 = k12 / 3, k2 = k12 % 3;
        if (n < 30) {
            const int k4 = (n < 10) ? 0 : ((n < 20) ? 1 : 2);
            const int co = n - 10 * k4;
            const int i1 = swap ? k3 : k1, i2 = swap ? k4 : k2;
            const int i3 = swap ? k1 : k3, i4 = swap ? k2 : k4;
            const int widx = ((i1 * 3 + i2) * 3 + i3) * 3 + i4;
#pragma unroll
            for (int j = 0; j < 8; ++j) {
                const int k = hl * 8 + j;
                float wv = 0.f;
                if (layer == 0) { if (k == 0) wv = w1[co * 81 + widx]; }
                else if (layer == 1) { if (k < 10) wv = w2[(co * 10 + k) * 81 + widx]; }
                else { if (k < 10 && co == 0) wv = w3[k * 81 + widx]; }
                us[j] = f2bf(wv);
            }
        }
    } else {
        const int idx = gid - 6 * 27 * 64;       // 0..383
        int r = idx >> 6;                        // 0..5
        const int k3 = r % 3, swap = r / 3;
        if (n < 30) {
            const int k4 = (n < 10) ? 0 : ((n < 20) ? 1 : 2);
            const int co = n - 10 * k4;
#pragma unroll
            for (int j = 0; j < 8; ++j) {
                const int k12 = hl * 8 + j;
                if (k12 < 9) {
                    const int k1 = k12 / 3, k2 = k12 % 3;
                    const int i1 = swap ? k3 : k1, i2 = swap ? k4 : k2;
                    const int i3 = swap ? k1 : k3, i4 = swap ? k2 : k4;
                    const int widx = ((i1 * 3 + i2) * 3 + i3) * 3 + i4;
                    us[j] = f2bf(w1[co * 81 + widx]);
                }
            }
        }
    }
    u32* o = ft + (size_t)gid * 4;
    o[0] = (u32)us[0] | ((u32)us[1] << 16);
    o[1] = (u32)us[2] | ((u32)us[3] << 16);
    o[2] = (u32)us[4] | ((u32)us[5] << 16);
    o[3] = (u32)us[6] | ((u32)us[7] << 16);
}

// ---------------------------------------------------------------------------
// Zero halo positions (h' or t' in {0,31}) of all 1800 planes of y1 and y2.
__global__ __launch_bounds__(128) void zerok(u16* __restrict__ y1, u16* __restrict__ y2)
{
    const int pb = blockIdx.x, tid = threadIdx.x;
    if (tid >= 124) return;
    int hp, tp;
    if (tid < 32)      { hp = 0;        tp = tid; }
    else if (tid < 64) { hp = 31;       tp = tid - 32; }
    else if (tid < 94) { hp = tid - 63; tp = 0; }
    else               { hp = tid - 93; tp = 31; }
    const size_t off = (size_t)pb * PLANE + hp * 1024 + tp * 32;
    const uint4 z = make_uint4(0, 0, 0, 0);
    *(uint4*)((char*)y1 + off)      = z;
    *(uint4*)((char*)y1 + off + 16) = z;
    *(uint4*)((char*)y2 + off)      = z;
    *(uint4*)((char*)y2 + off + 16) = z;
}

// ---------------------------------------------------------------------------
// Layer 0, K-packed: one "tap", 12 MFMAs per wave (unchanged from R13).
__global__ __launch_bounds__(256, 4) void conv0_k(
    const float* __restrict__ x, const uint4* __restrict__ bt,
    const float* __restrict__ bias, void* __restrict__ outp)
{
    __shared__ float E[4][1056];
    const int wgid = blockIdx.x + S * blockIdx.y + 900 * blockIdx.z;
    const int id2  = (wgid & 7) * 450 + (wgid >> 3);
    const int half = id2 & 1;
    int sp = id2 >> 1;
    const int w1i = sp % S; sp /= S;
    const int h1  = sp % S;
    const int b   = sp / S;

    const int tid = threadIdx.x;
    const int lane = tid & 63, wv = tid >> 6;
    const int m = lane & 31, hl = lane >> 5;
    const int rbase = half * 15 + wv * 4;

    uint4 Bs[3];
#pragma unroll
    for (int ss = 0; ss < 3; ++ss) Bs[ss] = bt[ss * 64 + lane];

    int gof[9]; int gokm = 0;
#pragma unroll
    for (int k12 = 0; k12 < 9; ++k12) {
        const int g1 = h1 + k12 / 3 - 1, g2 = w1i + k12 % 3 - 1;
        gof[k12] = 0;
        if (g1 >= 0 && g1 < S && g2 >= 0 && g2 < S) {
            gof[k12] = (g1 * S + g2) * 900; gokm |= 1 << k12;
        }
    }
    const float* xb = x + (size_t)b * S4;

    uint4 F[6];
#pragma unroll
    for (int f = 0; f < 6; ++f) {
        const int hp = rbase + f;
        const bool rk = (hp >= 1 && hp <= 30 && m >= 1 && m <= 30);
        const int ro = (hp - 1) * 30 + (m - 1);
        u16 av[8];
#pragma unroll
        for (int j = 0; j < 8; ++j) av[j] = 0;
        if (hl == 0) {
#pragma unroll
            for (int j = 0; j < 8; ++j) {
                float v = 0.f;
                if (rk && ((gokm >> j) & 1)) v = xb[gof[j] + ro];
                av[j] = f2bf(v);
            }
        } else {
            float v = 0.f;
            if (rk && ((gokm >> 8) & 1)) v = xb[gof[8] + ro];
            av[0] = f2bf(v);
        }
        F[f] = make_uint4((u32)av[0] | ((u32)av[1] << 16),
                          (u32)av[2] | ((u32)av[3] << 16),
                          (u32)av[4] | ((u32)av[5] << 16),
                          (u32)av[6] | ((u32)av[7] << 16));
    }

    f32x16 acc[4];
#pragma unroll
    for (int r = 0; r < 4; ++r)
#pragma unroll
        for (int e = 0; e < 16; ++e) acc[r][e] = 0.f;
#pragma unroll
    for (int ss = 0; ss < 3; ++ss)
#pragma unroll
        for (int r = 0; r < 4; ++r)
            acc[r] = __builtin_amdgcn_mfma_f32_32x32x16_bf16(
                __builtin_bit_cast(bf16x8, F[r + ss]),
                __builtin_bit_cast(bf16x8, Bs[ss]), acc[r], 0, 0, 0);

    float* Ew = E[wv];
    for (int r = 0; r < 4; ++r) {
        if (wv == 3 && r == 3) continue;
#pragma unroll
        for (int gq = 0; gq < 4; ++gq)
#pragma unroll
            for (int r4 = 0; r4 < 4; ++r4)
                Ew[m * 33 + 4 * hl + 8 * gq + r4] = acc[r][gq * 4 + r4];

        const int h2 = rbase + r;
        char* pl = (char*)outp + ((size_t)b * 900 + h1 * S + w1i) * PLANE
                   + (size_t)(h2 + 1) * 1024;
        const int t = lane >> 1, h8 = lane & 1;
        if (t < 30) {
            u32 wo[4];
#pragma unroll
            for (int p = 0; p < 4; ++p) {
                const int c0 = 8 * h8 + 2 * p, c1 = c0 + 1;
                float v0 = 0.f, v1 = 0.f;
                if (c0 < 10)
                    v0 = fmaxf(Ew[c0 * 33 + t] + Ew[(10 + c0) * 33 + t + 1]
                             + Ew[(20 + c0) * 33 + t + 2] + bias[c0], 0.f);
                if (c1 < 10)
                    v1 = fmaxf(Ew[c1 * 33 + t] + Ew[(10 + c1) * 33 + t + 1]
                             + Ew[(20 + c1) * 33 + t + 2] + bias[c1], 0.f);
                wo[p] = (u32)f2bf(v0) | ((u32)f2bf(v1) << 16);
            }
            *(uint4*)(pl + (t + 1) * 32 + h8 * 16) =
                make_uint4(wo[0], wo[1], wo[2], wo[3]);
        }
    }
}

// ---------------------------------------------------------------------------
// Layers 1/2: R13 tap loop (rotate depth-1 prefetch on A), B-table staged
// to LDS once per block; tap-loop B reads via ds_read_b128 (DS pipe).
// Wave wv owns rows rbase..rbase+3 (wave 3 row 3 junk, uniform body).
template<int LAYER, bool ACCUM>
__global__ __launch_bounds__(256, 2) void conv_k(
    const void* __restrict__ inp, const u32* __restrict__ ftab,
    const float* __restrict__ bias, void* __restrict__ outp)
{
    __shared__ float E[4][1056];          // per-wave epilogue scratch
    __shared__ uint4 BT[1728];            // [k12(9)][k3(3)][lane(64)]

    const int tid = threadIdx.x;
    // ---- stage B table to LDS (27.6 KB, once per block) ----
    {
        const uint4* g = (const uint4*)ftab;
#pragma unroll
        for (int j = 0; j < 7; ++j) {
            const int idx = j * 256 + tid;
            if (idx < 1728) BT[idx] = g[idx];
        }
    }
    __syncthreads();

    const int wgid = blockIdx.x + S * blockIdx.y + 900 * blockIdx.z;
    const int id2  = (wgid & 7) * 450 + (wgid >> 3);
    const int half = id2 & 1;
    int sp = id2 >> 1;
    const int w1i = sp % S; sp /= S;
    const int h1  = sp % S;
    const int b   = sp / S;

    const int lane = tid & 63, wv = tid >> 6;
    const int m = lane & 31, hl = lane >> 5;
    const int rbase = half * 15 + wv * 4;

    int rofs[6];
#pragma unroll
    for (int f = 0; f < 6; ++f) {
        int rr = rbase + f; if (rr > 31) rr = 31;
        rofs[f] = rr * 1024;
    }

    int kl[9], nk = 0;
#pragma unroll
    for (int k12 = 0; k12 < 9; ++k12) {
        const int g1 = h1 + k12 / 3 - 1, g2 = w1i + k12 % 3 - 1;
        if (g1 >= 0 && g1 < S && g2 >= 0 && g2 < S)
            kl[nk++] = (g1 * S + g2) | (k12 << 10);
    }

    f32x16 acc[4];
#pragma unroll
    for (int r = 0; r < 4; ++r)
#pragma unroll
        for (int e = 0; e < 16; ++e) acc[r][e] = 0.f;

    auto loadA = [&](uint4* Fd, int g) {
        const char* P = (const char*)inp + ((size_t)b * 900 + g) * PLANE
                        + m * 32 + hl * 16;
#pragma unroll
        for (int f = 0; f < 6; ++f)
            Fd[f] = *(const uint4*)(P + rofs[f]);
    };

    uint4 B0[3];
    {
        const int k0 = kl[0] >> 10;
#pragma unroll
        for (int f = 0; f < 3; ++f) B0[f] = BT[(k0 * 3 + f) * 64 + lane];
    }
    uint4 F[6];
    loadA(F, kl[0] & 1023);

    for (int ki = 0; ki + 1 < nk; ++ki) {
        const int gn = kl[ki + 1] & 1023, kn = kl[ki + 1] >> 10;
        uint4 FN[6];
        loadA(FN, gn);
        uint4 BN[3];
#pragma unroll
        for (int f = 0; f < 3; ++f) BN[f] = BT[(kn * 3 + f) * 64 + lane];

        // s-outer / r-inner: 4 independent MFMAs between dependent pairs
#pragma unroll
        for (int ss = 0; ss < 3; ++ss)
#pragma unroll
            for (int r = 0; r < 4; ++r)
                acc[r] = __builtin_amdgcn_mfma_f32_32x32x16_bf16(
                    __builtin_bit_cast(bf16x8, F[r + ss]),
                    __builtin_bit_cast(bf16x8, B0[ss]), acc[r], 0, 0, 0);

#pragma unroll
        for (int f = 0; f < 6; ++f) F[f] = FN[f];
#pragma unroll
        for (int f = 0; f < 3; ++f) B0[f] = BN[f];
    }
#pragma unroll
    for (int ss = 0; ss < 3; ++ss)
#pragma unroll
        for (int r = 0; r < 4; ++r)
            acc[r] = __builtin_amdgcn_mfma_f32_32x32x16_bf16(
                __builtin_bit_cast(bf16x8, F[r + ss]),
                __builtin_bit_cast(bf16x8, B0[ss]), acc[r], 0, 0, 0);

    // ---- epilogue: per-wave LDS transpose, combine k4 shifts (barrier-free)
    float* Ew = E[wv];
    for (int r = 0; r < 4; ++r) {
        if (wv == 3 && r == 3) continue;
#pragma unroll
        for (int gq = 0; gq < 4; ++gq)
#pragma unroll
            for (int r4 = 0; r4 < 4; ++r4)
                Ew[m * 33 + 4 * hl + 8 * gq + r4] = acc[r][gq * 4 + r4];

        const int h2 = rbase + r;
        if (LAYER <= 1) {
            char* pl = (char*)outp + ((size_t)b * 900 + h1 * S + w1i) * PLANE
                       + (size_t)(h2 + 1) * 1024;
            const int t = lane >> 1, h8 = lane & 1;
            if (t < 30) {
                u32 wo[4];
#pragma unroll
                for (int p = 0; p < 4; ++p) {
                    const int c0 = 8 * h8 + 2 * p, c1 = c0 + 1;
                    float v0 = 0.f, v1 = 0.f;
                    if (c0 < 10)
                        v0 = fmaxf(Ew[c0 * 33 + t] + Ew[(10 + c0) * 33 + t + 1]
                                 + Ew[(20 + c0) * 33 + t + 2] + bias[c0], 0.f);
                    if (c1 < 10)
                        v1 = fmaxf(Ew[c1 * 33 + t] + Ew[(10 + c1) * 33 + t + 1]
                                 + Ew[(20 + c1) * 33 + t + 2] + bias[c1], 0.f);
                    wo[p] = (u32)f2bf(v0) | ((u32)f2bf(v1) << 16);
                }
                *(uint4*)(pl + (t + 1) * 32 + h8 * 16) =
                    make_uint4(wo[0], wo[1], wo[2], wo[3]);
            }
        } else {
            if (lane < 30) {
                const int t = lane;
                float v = Ew[t] + Ew[330 + t + 1] + Ew[660 + t + 2] + bias[0];
                v = fmaxf(v, 0.f);
                float* o = (float*)outp + (size_t)b * S4
                           + (size_t)(h1 * S + w1i) * 900 + h2 * 30 + t;
                if (ACCUM) *o += v; else *o = v;
            }
        }
    }
}

// ---------------------------------------------------------------------------
extern "C" void kernel_launch(void* const* d_in, const int* in_sizes, int n_in,
                              void* d_out, int out_size, void* d_ws, size_t ws_size,
                              hipStream_t stream)
{
    const float* x   = (const float*)d_in[0];
    const float* w1p = (const float*)d_in[1];
    const float* b1p = (const float*)d_in[2];
    const float* w2p = (const float*)d_in[3];
    const float* b2p = (const float*)d_in[4];
    const float* w3p = (const float*)d_in[5];
    const float* b3p = (const float*)d_in[6];
    float* out = (float*)d_out;

    // ws: fragtab (6*27*64 + 2*3*64) uint4 = 172032 B | y1 59 MB | y2 59 MB
    u32* ft = (u32*)d_ws;
    const uint4* ftL0 = (const uint4*)d_ws + 6 * 27 * 64;
    u16* y1 = (u16*)((char*)d_ws + 172032);
    u16* y2 = (u16*)((char*)y1 + YBYTES);

    fragprep_k<<<42, 256, 0, stream>>>(ft, w1p, w2p, w3p);
    zerok<<<1800, 128, 0, stream>>>(y1, y2);

    dim3 grid(S, S, 4), blk(256);
    for (int br = 0; br < 2; ++br) {
        const u32* f2 = ft + (size_t)(2 + br) * 27 * 64 * 4;
        const u32* f3 = ft + (size_t)(4 + br) * 27 * 64 * 4;
        conv0_k<<<grid, blk, 0, stream>>>(x, ftL0 + br * 192, b1p, (void*)y1);
        conv_k<1, false><<<grid, blk, 0, stream>>>(y1, f2, b2p, (void*)y2);
        if (br == 0)
            conv_k<2, false><<<grid, blk, 0, stream>>>(y2, f3, b3p, (void*)out);
        else
            conv_k<2, true><<<grid, blk, 0, stream>>>(y2, f3, b3p, (void*)out);
    }
}